// Round 19
// baseline (375.625 us; speedup 1.0000x reference)
//
#include <hip/hip_runtime.h>
#include <hip/hip_bf16.h>

#define BB 2
#define TT 2048
#define CCH 1024
#define HH 16
#define HD 64
#define EE 8
#define FF 2048
#define NTOK (BB*TT)

typedef __bf16 bf16x8 __attribute__((ext_vector_type(8)));
typedef float f32x4 __attribute__((ext_vector_type(4)));
typedef unsigned int u32;
typedef const u32 __attribute__((address_space(1)))* gads;
typedef u32 __attribute__((address_space(3)))* lads;

static __device__ __forceinline__ unsigned short f2bf(float f) {
  union { float f; unsigned u; } v; v.f = f;
  unsigned u = v.u;
  u += 0x7fffu + ((u >> 16) & 1u);
  return (unsigned short)(u >> 16);
}
static __device__ __forceinline__ float bf2f(unsigned short h) {
  union { unsigned u; float f; } v; v.u = ((unsigned)h) << 16;
  return v.f;
}

// ---------------- transpose fp32 (R x C) -> bf16 (C x R), batched over z ----
__global__ __launch_bounds__(256) void k_transpose(const float* __restrict__ in,
    unsigned short* __restrict__ out, int R, int Cc) {
  __shared__ float tile[32][33];
  size_t zoff = (size_t)blockIdx.z * (size_t)R * (size_t)Cc;
  int r0 = blockIdx.y * 32, c0 = blockIdx.x * 32;
  int tx = threadIdx.x, ty = threadIdx.y;
#pragma unroll
  for (int ii = 0; ii < 4; ++ii) {
    int i = ty + ii * 8;
    tile[i][tx] = in[zoff + (size_t)(r0 + i) * Cc + c0 + tx];
  }
  __syncthreads();
#pragma unroll
  for (int ii = 0; ii < 4; ++ii) {
    int i = ty + ii * 8;
    out[zoff + (size_t)(c0 + i) * R + r0 + tx] = f2bf(tile[tx][i]);
  }
}

// ---------------- layernorm row kernel: fp32 in -> bf16 out ----------------
__global__ __launch_bounds__(256) void k_ln(const float* __restrict__ x,
    const float* __restrict__ w, unsigned short* __restrict__ out) {
  int row = blockIdx.x;
  const float* xr = x + (size_t)row * CCH;
  int tid = threadIdx.x;
  float4 v = *(const float4*)&xr[tid * 4];
  float s = v.x + v.y + v.z + v.w;
  float ss = v.x * v.x + v.y * v.y + v.z * v.z + v.w * v.w;
#pragma unroll
  for (int off = 32; off; off >>= 1) { s += __shfl_xor(s, off); ss += __shfl_xor(ss, off); }
  __shared__ float red[8];
  int wv = tid >> 6, l = tid & 63;
  if (l == 0) { red[wv] = s; red[4 + wv] = ss; }
  __syncthreads();
  s = red[0] + red[1] + red[2] + red[3];
  ss = red[4] + red[5] + red[6] + red[7];
  float mean = s * (1.f / CCH);
  float var = ss * (1.f / CCH) - mean * mean;
  float inv = rsqrtf(var + 1e-5f);
  float4 w4 = *(const float4*)&w[tid * 4];
  ushort4 o;
  o.x = f2bf((v.x - mean) * inv * w4.x);
  o.y = f2bf((v.y - mean) * inv * w4.y);
  o.z = f2bf((v.z - mean) * inv * w4.z);
  o.w = f2bf((v.w - mean) * inv * w4.w);
  *(ushort4*)&out[(size_t)row * CCH + tid * 4] = o;
}

// ---------------- fused LN2 + router: LN(bf16 out) + logits + top2 ---------
__global__ __launch_bounds__(256) void k_ln2_router(const float* __restrict__ x,
    const float* __restrict__ w, const float* __restrict__ rw,
    unsigned short* __restrict__ out, int* __restrict__ sel,
    float* __restrict__ selw) {
  int row = blockIdx.x;
  const float* xr = x + (size_t)row * CCH;
  int tid = threadIdx.x;
  float4 v = *(const float4*)&xr[tid * 4];
  float s = v.x + v.y + v.z + v.w;
  float ss = v.x * v.x + v.y * v.y + v.z * v.z + v.w * v.w;
#pragma unroll
  for (int off = 32; off; off >>= 1) { s += __shfl_xor(s, off); ss += __shfl_xor(ss, off); }
  __shared__ float red[8];
  __shared__ float red2[4][8];
  int wv = tid >> 6, l = tid & 63;
  if (l == 0) { red[wv] = s; red[4 + wv] = ss; }
  __syncthreads();
  s = red[0] + red[1] + red[2] + red[3];
  ss = red[4] + red[5] + red[6] + red[7];
  float mean = s * (1.f / CCH);
  float var = ss * (1.f / CCH) - mean * mean;
  float inv = rsqrtf(var + 1e-5f);
  float4 w4 = *(const float4*)&w[tid * 4];
  float nv0 = (v.x - mean) * inv * w4.x;
  float nv1 = (v.y - mean) * inv * w4.y;
  float nv2 = (v.z - mean) * inv * w4.z;
  float nv3 = (v.w - mean) * inv * w4.w;
  ushort4 o;
  o.x = f2bf(nv0); o.y = f2bf(nv1); o.z = f2bf(nv2); o.w = f2bf(nv3);
  *(ushort4*)&out[(size_t)row * CCH + tid * 4] = o;
  const float* rr = rw + (size_t)tid * 4 * EE;
  float lg[8];
#pragma unroll
  for (int e = 0; e < 8; ++e)
    lg[e] = nv0 * rr[e] + nv1 * rr[8 + e] + nv2 * rr[16 + e] + nv3 * rr[24 + e];
#pragma unroll
  for (int e = 0; e < 8; ++e) {
    float t = lg[e];
#pragma unroll
    for (int off = 32; off; off >>= 1) t += __shfl_xor(t, off);
    lg[e] = t;
  }
  if (l == 0) {
#pragma unroll
    for (int e = 0; e < 8; ++e) red2[wv][e] = lg[e];
  }
  __syncthreads();
  if (tid == 0) {
    float logit[8];
#pragma unroll
    for (int e = 0; e < 8; ++e)
      logit[e] = red2[0][e] + red2[1][e] + red2[2][e] + red2[3][e];
    float m1 = logit[0]; int i1 = 0;
#pragma unroll
    for (int e = 1; e < 8; ++e) if (logit[e] > m1) { m1 = logit[e]; i1 = e; }
    float m2 = -INFINITY; int i2 = 0;
#pragma unroll
    for (int e = 0; e < 8; ++e) if (e != i1 && logit[e] > m2) { m2 = logit[e]; i2 = e; }
    float w1v = 1.f / (1.f + __expf(m2 - m1));
    sel[row * 2] = i1; sel[row * 2 + 1] = i2;
    selw[row * 2] = w1v; selw[row * 2 + 1] = 1.f - w1v;
  }
}

// ---------------- 128x128 GEMM, single-buffer, TLP-first -------------------
// EPI 0: bf16 out (QKV)    EPI 2: grouped gather, fast-gelu -> bf16 (MoE up)
#define CSP 140
#define CFP 70
template<int EPI>
__global__ __launch_bounds__(256, 4) void k_gemm128(
    const unsigned short* __restrict__ A, const unsigned short* __restrict__ BT,
    unsigned short* __restrict__ Cb, float* __restrict__ Cf,
    const float* __restrict__ resid, int M, int N, int K,
    const int* __restrict__ tokarr, const int* __restrict__ slotarr,
    const float* __restrict__ wgtarr, const int* __restrict__ offs,
    const int* __restrict__ counts, const int* __restrict__ tmap)
{
  __shared__ __align__(16) char pool[35840];
  unsigned short* As = (unsigned short*)pool;
  unsigned short* Bs = (unsigned short*)(pool + 16384);

  int mb, nb, e = 0, off = 0, cnt = M;
  if (EPI >= 2) {
    int tm = blockIdx.x;
    if (tm >= tmap[8]) return;
    e = 0;
    while (tm >= tmap[e + 1]) ++e;
    mb = tm - tmap[e];
    nb = blockIdx.y;
    cnt = counts[e]; off = offs[e];
  } else {
    int gx = gridDim.x, gy = gridDim.y;
    int nwg = gx * gy;
    int orig = blockIdx.y * gx + blockIdx.x;
    int q = nwg >> 3, r = nwg & 7;
    int xcd = orig & 7, idx = orig >> 3;
    int wk = (xcd < r ? xcd * (q + 1) : r * (q + 1) + (xcd - r) * q) + idx;
    nb = wk % gy; mb = wk / gy;
  }
  int m0 = mb * 128, n0 = nb * 128;

  int tid = threadIdx.x, l = tid & 63, w = tid >> 6;
  int scol = (((l & 7) ^ ((l >> 3) & 7)) * 8);
  const unsigned short* aptr[4];
  const unsigned short* bptr[4];
  const unsigned short* bbase = BT + (size_t)e * (size_t)N * K;
#pragma unroll
  for (int i = 0; i < 4; ++i) {
    int row = (w * 4 + i) * 8 + (l >> 3);
    int ra;
    if (EPI == 2)      ra = tokarr[off + min(m0 + row, cnt - 1)];
    else               ra = m0 + row;
    aptr[i] = A + (size_t)ra * K + scol;
    bptr[i] = bbase + (size_t)(n0 + row) * K + scol;
  }

  int wr = (w >> 1) * 64, wc = (w & 1) * 64;
  int frow = l & 15;
  int fkB = (l >> 4) * 16;
  int swz = (frow & 7) << 4;
  f32x4 acc[4][4] = {};

  for (int k0 = 0; k0 < K; k0 += 64) {
#pragma unroll
    for (int i = 0; i < 4; ++i) {
      int j = w * 4 + i;
      __builtin_amdgcn_global_load_lds((gads)(const void*)(aptr[i] + k0),
                                       (lads)(void*)(As + j * 512), 16, 0, 0);
      __builtin_amdgcn_global_load_lds((gads)(const void*)(bptr[i] + k0),
                                       (lads)(void*)(Bs + j * 512), 16, 0, 0);
    }
    __syncthreads();
    const char* ab = (const char*)As;
    const char* bb = (const char*)Bs;
#pragma unroll
    for (int kk = 0; kk < 2; ++kk) {
      int inr = (kk * 64 + fkB) ^ swz;
      bf16x8 af[4], bfr[4];
#pragma unroll
      for (int mi = 0; mi < 4; ++mi)
        af[mi] = *(const bf16x8*)(ab + (wr + mi * 16 + frow) * 128 + inr);
#pragma unroll
      for (int ni = 0; ni < 4; ++ni)
        bfr[ni] = *(const bf16x8*)(bb + (wc + ni * 16 + frow) * 128 + inr);
#pragma unroll
      for (int mi = 0; mi < 4; ++mi)
#pragma unroll
        for (int ni = 0; ni < 4; ++ni)
          acc[mi][ni] = __builtin_amdgcn_mfma_f32_16x16x32_bf16(af[mi], bfr[ni],
                                                                acc[mi][ni], 0, 0, 0);
    }
    __syncthreads();
  }

  int g4 = (l >> 4) * 4, cl = l & 15;
  unsigned short* Cs = (unsigned short*)pool;
#pragma unroll
  for (int mi = 0; mi < 4; ++mi)
#pragma unroll
    for (int ni = 0; ni < 4; ++ni)
#pragma unroll
      for (int r2 = 0; r2 < 4; ++r2) {
        float v = acc[mi][ni][r2];
        if (EPI == 2) {
          float u2 = 1.5957691216f * v * (1.f + 0.044715f * v * v);
          float ex = __expf(u2);
          v = v - v / (ex + 1.f);
        }
        Cs[(wr + mi * 16 + g4 + r2) * CSP + wc + ni * 16 + cl] = f2bf(v);
      }
  __syncthreads();
  int row = tid >> 1, c0 = (tid & 1) * 64;
  if (EPI == 0 || m0 + row < cnt) {
    size_t grow = (EPI == 2) ? (size_t)(off + m0 + row) : (size_t)(m0 + row);
    unsigned short* dst = Cb + grow * N + n0 + c0;
#pragma unroll
    for (int j = 0; j < 8; ++j)
      ((uint4*)dst)[j] = *(const uint4*)&Cs[row * CSP + c0 + j * 8];
  }
}

// ---------------- 64x128 GEMM for occupancy-starved dispatches -------------
// Same structure as k_gemm128, BM=64: 4 waves x 32x64 sub-tiles, 24KB LDS.
// EPI 1: f32 out = acc + resid (proj+residual), grid (M/64, N/128)
// EPI 3: grouped (tmap64), bf16 out, wg applied at coalesced read (MoE down)
template<int EPI>
__global__ __launch_bounds__(256, 4) void k_gemm64(
    const unsigned short* __restrict__ A, const unsigned short* __restrict__ BT,
    unsigned short* __restrict__ Cb, float* __restrict__ Cf,
    const float* __restrict__ resid, int M, int N, int K,
    const int* __restrict__ tokarr, const int* __restrict__ slotarr,
    const float* __restrict__ wgtarr, const int* __restrict__ offs,
    const int* __restrict__ counts, const int* __restrict__ tmap64)
{
  __shared__ __align__(16) char pool[24576];
  unsigned short* As = (unsigned short*)pool;            // 64x64 = 8KB
  unsigned short* Bs = (unsigned short*)(pool + 8192);   // 128x64 = 16KB

  int mb, nb, e = 0, off = 0, cnt = M;
  if (EPI == 3) {
    int tm = blockIdx.x;
    if (tm >= tmap64[8]) return;
    e = 0;
    while (tm >= tmap64[e + 1]) ++e;
    mb = tm - tmap64[e];
    nb = blockIdx.y;
    cnt = counts[e]; off = offs[e];
  } else {
    int gx = gridDim.x, gy = gridDim.y;
    int nwg = gx * gy;
    int orig = blockIdx.y * gx + blockIdx.x;
    int q = nwg >> 3, r = nwg & 7;
    int xcd = orig & 7, idx = orig >> 3;
    int wk = (xcd < r ? xcd * (q + 1) : r * (q + 1) + (xcd - r) * q) + idx;
    nb = wk % gy; mb = wk / gy;
  }
  int m0 = mb * 64, n0 = nb * 128;

  int tid = threadIdx.x, l = tid & 63, w = tid >> 6;
  int scol = (((l & 7) ^ ((l >> 3) & 7)) * 8);
  const unsigned short* aptr[2];
  const unsigned short* bptr[4];
  const unsigned short* bbase = BT + (size_t)e * (size_t)N * K;
#pragma unroll
  for (int i = 0; i < 2; ++i) {
    int row = (w * 2 + i) * 8 + (l >> 3);
    int ra;
    if (EPI == 3) ra = off + min(m0 + row, cnt - 1);
    else          ra = m0 + row;
    aptr[i] = A + (size_t)ra * K + scol;
  }
#pragma unroll
  for (int i = 0; i < 4; ++i) {
    int row = (w * 4 + i) * 8 + (l >> 3);
    bptr[i] = bbase + (size_t)(n0 + row) * K + scol;
  }

  int wr = (w >> 1) * 32, wc = (w & 1) * 64;
  int frow = l & 15;
  int fkB = (l >> 4) * 16;
  int swz = (frow & 7) << 4;
  f32x4 acc[2][4] = {};

  for (int k0 = 0; k0 < K; k0 += 64) {
#pragma unroll
    for (int i = 0; i < 2; ++i) {
      int j = w * 2 + i;
      __builtin_amdgcn_global_load_lds((gads)(const void*)(aptr[i] + k0),
                                       (lads)(void*)(As + j * 512), 16, 0, 0);
    }
#pragma unroll
    for (int i = 0; i < 4; ++i) {
      int j = w * 4 + i;
      __builtin_amdgcn_global_load_lds((gads)(const void*)(bptr[i] + k0),
                                       (lads)(void*)(Bs + j * 512), 16, 0, 0);
    }
    __syncthreads();
    const char* ab = (const char*)As;
    const char* bb = (const char*)Bs;
#pragma unroll
    for (int kk = 0; kk < 2; ++kk) {
      int inr = (kk * 64 + fkB) ^ swz;
      bf16x8 af[2], bfr[4];
#pragma unroll
      for (int mi = 0; mi < 2; ++mi)
        af[mi] = *(const bf16x8*)(ab + (wr + mi * 16 + frow) * 128 + inr);
#pragma unroll
      for (int ni = 0; ni < 4; ++ni)
        bfr[ni] = *(const bf16x8*)(bb + (wc + ni * 16 + frow) * 128 + inr);
#pragma unroll
      for (int mi = 0; mi < 2; ++mi)
#pragma unroll
        for (int ni = 0; ni < 4; ++ni)
          acc[mi][ni] = __builtin_amdgcn_mfma_f32_16x16x32_bf16(af[mi], bfr[ni],
                                                                acc[mi][ni], 0, 0, 0);
    }
    __syncthreads();
  }

  int g4 = (l >> 4) * 4, cl = l & 15;

  if (EPI == 3) {
    // bf16 bounce [64][CSP], wg applied at coalesced read
    unsigned short* Cs = (unsigned short*)pool;
#pragma unroll
    for (int mi = 0; mi < 2; ++mi)
#pragma unroll
      for (int ni = 0; ni < 4; ++ni)
#pragma unroll
        for (int r2 = 0; r2 < 4; ++r2)
          Cs[(wr + mi * 16 + g4 + r2) * CSP + wc + ni * 16 + cl] = f2bf(acc[mi][ni][r2]);
    __syncthreads();
    int row = tid >> 2, c0 = (tid & 3) * 32;
    if (m0 + row < cnt) {
      int fl = off + m0 + row;
      int tok = tokarr[fl], slot = slotarr[fl];
      float wg = wgtarr[fl];
      unsigned short* dst = Cb + ((size_t)tok * 2 + slot) * N + n0 + c0;
#pragma unroll
      for (int j = 0; j < 4; ++j) {
        uint4 pk = *(const uint4*)&Cs[row * CSP + c0 + j * 8];
        unsigned short* sp = (unsigned short*)&pk;
        ushort4 o0, o1;
        o0.x = f2bf(bf2f(sp[0]) * wg); o0.y = f2bf(bf2f(sp[1]) * wg);
        o0.z = f2bf(bf2f(sp[2]) * wg); o0.w = f2bf(bf2f(sp[3]) * wg);
        o1.x = f2bf(bf2f(sp[4]) * wg); o1.y = f2bf(bf2f(sp[5]) * wg);
        o1.z = f2bf(bf2f(sp[6]) * wg); o1.w = f2bf(bf2f(sp[7]) * wg);
        *(ushort4*)&dst[j * 8] = o0;
        *(ushort4*)&dst[j * 8 + 4] = o1;
      }
    }
  } else {
    // EPI 1: f32 out = acc + resid, two half-passes through [64][CFP]
    float* Csf = (float*)pool;
#pragma unroll
    for (int p = 0; p < 2; ++p) {
      __syncthreads();
      if ((w & 1) == p) {
#pragma unroll
        for (int mi = 0; mi < 2; ++mi)
#pragma unroll
          for (int ni = 0; ni < 4; ++ni)
#pragma unroll
            for (int r2 = 0; r2 < 4; ++r2)
              Csf[(wr + mi * 16 + g4 + r2) * CFP + ni * 16 + cl] = acc[mi][ni][r2];
      }
      __syncthreads();
      int row = tid >> 2, c0 = (tid & 3) * 16;
      int gcol = n0 + p * 64 + c0;
      float* dst = Cf + (size_t)(m0 + row) * N + gcol;
      const float* rsd = resid + (size_t)(m0 + row) * N + gcol;
#pragma unroll
      for (int j = 0; j < 4; ++j) {
        float4 v = *(const float4*)&Csf[row * CFP + c0 + j * 4];
        float4 rr = ((const float4*)rsd)[j];
        v.x += rr.x; v.y += rr.y; v.z += rr.z; v.w += rr.w;
        ((float4*)dst)[j] = v;
      }
    }
  }
}

// ---------------- MFMA flash attention, KV-split (r16/r18 proven) ----------
__device__ const unsigned char g_witab[48] = {
  124,125,120, 62, 121,116,117,112, 58, 113,108,109,104, 54,
  105,100,101, 96, 50,  97, 92, 93, 88, 46,  89, 84, 85, 80, 42,
   81, 76, 77, 72, 38,  73, 68, 69, 64, 34,  65, 30, 26, 22, 18, 14, 10, 6, 2
};

__global__ __launch_bounds__(256) void k_attn_mfma(const unsigned short* __restrict__ qkv,
    unsigned short* __restrict__ yout, float* __restrict__ Opart, float* __restrict__ ml)
{
  int fblk = blockIdx.x;
  int xcd = fblk & 7, s = fblk >> 3;
  int hbl = s & 3;
  int h = xcd + 8 * (hbl & 1);
  int b = hbl >> 1;
  int item = s >> 2;
  int v = g_witab[item];
  int qt = v >> 2, code = v & 3;
  bool split = (code != 2);
  int h1 = (qt + 2) >> 1;
  int kb0 = (code == 1) ? h1 : 0;
  int kb1 = (code == 0) ? h1 : (qt + 1);
  int q0 = qt * 64;

  int tid = threadIdx.x, l = tid & 63, w = tid >> 6;
  const size_t rs = 3 * CCH;

  __shared__ __align__(16) unsigned short Ks[64][72];
  __shared__ __align__(16) unsigned short VtL[64 * 72];
  __shared__ __align__(16) unsigned short Ps[4][16][72];

  int frow = l & 15, fk = (l >> 4) * 8;
  int g4 = l >> 4;
  int kr = tid >> 2, kc0 = (tid & 3) * 8;
  int vr = tid >> 2, vc0 = (tid & 3) * 16;
  int vphys = (((vr >> 3) + 2 * (tid & 3)) & 7) * 8 + (vr & 7);

  const unsigned short* qp = qkv + (size_t)((size_t)b * TT + q0 + w * 16 + frow) * rs + h * HD;
  bf16x8 qf0 = *(const bf16x8*)&qp[fk];
  bf16x8 qf1 = *(const bf16x8*)&qp[32 + fk];
  {
    unsigned short* q0s = (unsigned short*)&qf0;
    unsigned short* q1s = (unsigned short*)&qf1;
#pragma unroll
    for (int j = 0; j < 8; ++j) {
      q0s[j] = f2bf(bf2f(q0s[j]) * 0.125f);
      q1s[j] = f2bf(bf2f(q1s[j]) * 0.125f);
    }
  }

  f32x4 oacc[4] = {};
  float mrow[4] = {-INFINITY, -INFINITY, -INFINITY, -INFINITY};
  float lrow[4] = {};

  uint4 rk0, rk1, rv0, rv1;
  {
    int k0 = kb0 * 64;
    const unsigned short* kp = qkv + (size_t)((size_t)b * TT + k0 + kr) * rs + CCH + h * HD;
    rk0 = *(const uint4*)&kp[kc0];
    rk1 = *(const uint4*)&kp[kc0 + 32];
    const unsigned short* vp = qkv + (size_t)((size_t)b * TT + k0 + vr) * rs + 2 * CCH + h * HD + vc0;
    rv0 = *(const uint4*)&vp[0];
    rv1 = *(const uint4*)&vp[8];
  }

  for (int kb = kb0; kb < kb1; ++kb) {
    __syncthreads();
    *(uint4*)&Ks[kr][kc0]      = rk0;
    *(uint4*)&Ks[kr][kc0 + 32] = rk1;
    {
      unsigned short tmp[16];
      *(uint4*)&tmp[0] = rv0; *(uint4*)&tmp[8] = rv1;
#pragma unroll
      for (int j = 0; j < 16; ++j) VtL[(vc0 + j) * 72 + vphys] = tmp[j];
    }
    __syncthreads();
    if (kb + 1 < kb1) {
      int k0n = (kb + 1) * 64;
      const unsigned short* kp = qkv + (size_t)((size_t)b * TT + k0n + kr) * rs + CCH + h * HD;
      rk0 = *(const uint4*)&kp[kc0];
      rk1 = *(const uint4*)&kp[kc0 + 32];
      const unsigned short* vp = qkv + (size_t)((size_t)b * TT + k0n + vr) * rs + 2 * CCH + h * HD + vc0;
      rv0 = *(const uint4*)&vp[0];
      rv1 = *(const uint4*)&vp[8];
    }

    f32x4 sacc[4] = {};
    __builtin_amdgcn_s_setprio(1);
#pragma unroll
    for (int nb = 0; nb < 4; ++nb) {
      bf16x8 kf0 = *(const bf16x8*)&Ks[nb * 16 + frow][fk];
      bf16x8 kf1 = *(const bf16x8*)&Ks[nb * 16 + frow][32 + fk];
      sacc[nb] = __builtin_amdgcn_mfma_f32_16x16x32_bf16(qf0, kf0, sacc[nb], 0, 0, 0);
      sacc[nb] = __builtin_amdgcn_mfma_f32_16x16x32_bf16(qf1, kf1, sacc[nb], 0, 0, 0);
    }
    __builtin_amdgcn_s_setprio(0);

    bool diag = (kb == qt);
    float sv[4][4];
#pragma unroll
    for (int nb = 0; nb < 4; ++nb)
#pragma unroll
      for (int r = 0; r < 4; ++r) {
        float vv = sacc[nb][r];
        if (diag) {
          int ckv = nb * 16 + frow;
          int rq = w * 16 + 4 * g4 + r;
          if (ckv > rq) vv = -INFINITY;
        }
        sv[nb][r] = vv;
      }
    float fscale[4];
#pragma unroll
    for (int r = 0; r < 4; ++r) {
      float vm = fmaxf(fmaxf(sv[0][r], sv[1][r]), fmaxf(sv[2][r], sv[3][r]));
      vm = fmaxf(vm, __shfl_xor(vm, 1));
      vm = fmaxf(vm, __shfl_xor(vm, 2));
      vm = fmaxf(vm, __shfl_xor(vm, 4));
      vm = fmaxf(vm, __shfl_xor(vm, 8));
      float mnew = fmaxf(mrow[r], vm);
      float f = __expf(mrow[r] - mnew);
      mrow[r] = mnew;
      fscale[r] = f;
      float psum = 0.f;
#pragma unroll
      for (int nb = 0; nb < 4; ++nb) {
        float p = __expf(sv[nb][r] - mnew);
        sv[nb][r] = p;
        psum += p;
      }
      psum += __shfl_xor(psum, 1);
      psum += __shfl_xor(psum, 2);
      psum += __shfl_xor(psum, 4);
      psum += __shfl_xor(psum, 8);
      lrow[r] = lrow[r] * f + psum;
    }
#pragma unroll
    for (int nb = 0; nb < 4; ++nb)
#pragma unroll
      for (int r = 0; r < 4; ++r) {
        oacc[nb][r] *= fscale[r];
        Ps[w][4 * g4 + r][nb * 16 + frow] = f2bf(sv[nb][r]);
      }
    __builtin_amdgcn_s_setprio(1);
#pragma unroll
    for (int ks = 0; ks < 2; ++ks) {
      bf16x8 pa = *(const bf16x8*)&Ps[w][frow][ks * 32 + fk];
#pragma unroll
      for (int nb = 0; nb < 4; ++nb) {
        int vchunk = ((ks * 4 + (l >> 4) + 2 * nb) & 7) * 8;
        bf16x8 vb = *(const bf16x8*)&VtL[(nb * 16 + frow) * 72 + vchunk];
        oacc[nb] = __builtin_amdgcn_mfma_f32_16x16x32_bf16(pa, vb, oacc[nb], 0, 0, 0);
      }
    }
    __builtin_amdgcn_s_setprio(0);
  }

  if (!split) {
    unsigned short* yo = yout + (size_t)((size_t)b * TT + q0 + w * 16) * CCH + h * HD;
#pragma unroll
    for (int r = 0; r < 4; ++r) {
      float inv = 1.f / lrow[r];
      int row = 4 * g4 + r;
#pragma unroll
      for (int nb = 0; nb < 4; ++nb)
        yo[(size_t)row * CCH + nb * 16 + frow] = f2bf(oacc[nb][r] * inv);
    }
  } else {
    int hbg = b * HH + h;
    int pid = hbg * 16 + (qt - 16);
    int part = pid * 2 + code;
    float* Op = Opart + (size_t)part * 4096;
#pragma unroll
    for (int r = 0; r < 4; ++r) {
      int row = w * 16 + 4 * g4 + r;
#pragma unroll
      for (int nb = 0; nb < 4; ++nb)
        Op[row * 64 + nb * 16 + frow] = oacc[nb][r];
    }
    if (frow == 0) {
      float* mlp = ml + (size_t)part * 128;
#pragma unroll
      for (int r = 0; r < 4; ++r) {
        int row = w * 16 + 4 * g4 + r;
        mlp[row] = mrow[r];
        mlp[64 + row] = lrow[r];
      }
    }
  }
}

// ---------------- attention split-merge: combine two KV halves -------------
__global__ __launch_bounds__(256) void k_attn_merge(const float* __restrict__ Opart,
    const float* __restrict__ ml, unsigned short* __restrict__ yout)
{
  int pid = blockIdx.x;
  int hbg = pid >> 4;
  int qt = 16 + (pid & 15);
  int b = hbg >> 4, h = hbg & 15;
  int tid = threadIdx.x;
  int row = tid >> 2, c0 = (tid & 3) * 16;
  const float* mlA = ml + (size_t)(pid * 2) * 128;
  const float* mlB = mlA + 128;
  float mA = mlA[row], lA = mlA[64 + row];
  float mB = mlB[row], lB = mlB[64 + row];
  float m = fmaxf(mA, mB);
  float fA = __expf(mA - m), fB = __expf(mB - m);
  float inv = 1.f / (lA * fA + lB * fB);
  const float* OA = Opart + (size_t)(pid * 2) * 4096 + row * 64 + c0;
  const float* OB = OA + 4096;
  unsigned short* yo = yout + ((size_t)b * TT + qt * 64 + row) * CCH + h * HD + c0;
#pragma unroll
  for (int j4 = 0; j4 < 4; ++j4) {
    float4 a = *(const float4*)&OA[j4 * 4];
    float4 bb = *(const float4*)&OB[j4 * 4];
    ushort4 o;
    o.x = f2bf((a.x * fA + bb.x * fB) * inv);
    o.y = f2bf((a.y * fA + bb.y * fB) * inv);
    o.z = f2bf((a.z * fA + bb.z * fB) * inv);
    o.w = f2bf((a.w * fA + bb.w * fB) * inv);
    *(ushort4*)&yo[j4 * 4] = o;
  }
}

// ---------------- count: LDS histogram -> 1 atomic/expert/block ------------
__global__ __launch_bounds__(256) void k_count(const int* __restrict__ sel,
    int* __restrict__ counts_pad)
{
  __shared__ int hist[8];
  int tid = threadIdx.x;
  if (tid < 8) hist[tid] = 0;
  __syncthreads();
  int i = blockIdx.x * 256 + tid;
  atomicAdd(&hist[sel[i]], 1);
  __syncthreads();
  if (tid < 8) atomicAdd(&counts_pad[tid * 16], hist[tid]);
}

__global__ void k_offsets(const int* __restrict__ counts_pad, int* __restrict__ counts,
                          int* __restrict__ offs, int* __restrict__ cursors_pad,
                          int* __restrict__ tmap, int* __restrict__ tmap64) {
  if (threadIdx.x == 0 && blockIdx.x == 0) {
    int acc = 0, t = 0, t64 = 0;
    tmap[0] = 0; tmap64[0] = 0;
    for (int e = 0; e < 8; ++e) {
      int c = counts_pad[e * 16];
      counts[e] = c; offs[e] = acc; cursors_pad[e * 16] = acc; acc += c;
      t += (c + 127) >> 7;
      tmap[e + 1] = t;
      t64 += (c + 63) >> 6;
      tmap64[e + 1] = t64;
    }
  }
}

// ---------------- scatter: wave-aggregated ballot atomics ------------------
__global__ __launch_bounds__(256) void k_scatter(const int* __restrict__ sel,
    const float* __restrict__ selw, int* __restrict__ cursors_pad,
    int* __restrict__ tokarr, int* __restrict__ slotarr, float* __restrict__ wgtarr)
{
  int t = blockIdx.x * 256 + threadIdx.x;
  int l = threadIdx.x & 63;
#pragma unroll
  for (int s2 = 0; s2 < 2; ++s2) {
    int e = sel[t * 2 + s2];
    int pos = 0;
#pragma unroll
    for (int ex = 0; ex < 8; ++ex) {
      unsigned long long mask = __ballot(e == ex);
      if (e == ex) {
        int leader = __ffsll((long long)mask) - 1;
        int cntw = __popcll(mask);
        int base = 0;
        if (l == leader) base = atomicAdd(&cursors_pad[ex * 16], cntw);
        base = __shfl(base, leader);
        unsigned long long below = (l == 0) ? 0ull : (mask << (64 - l));
        pos = base + __popcll(below);
      }
    }
    tokarr[pos] = t; slotarr[pos] = s2; wgtarr[pos] = selw[t * 2 + s2];
  }
}

// ---------------- final combine: out = x2 + yp[:,0,:] + yp[:,1,:] (yp bf16)-
__global__ __launch_bounds__(256) void k_combine(const float* __restrict__ x2,
    const unsigned short* __restrict__ ypb, float* __restrict__ out)
{
  int i = blockIdx.x * 256 + threadIdx.x;
  int n = i >> 7, cw = i & 127;
  float4 a0 = ((const float4*)x2)[i * 2];
  float4 a1 = ((const float4*)x2)[i * 2 + 1];
  uint4 y0p = *(const uint4*)&ypb[((size_t)n * 2) * CCH + cw * 8];
  uint4 y1p = *(const uint4*)&ypb[((size_t)n * 2 + 1) * CCH + cw * 8];
  const unsigned short* y0 = (const unsigned short*)&y0p;
  const unsigned short* y1 = (const unsigned short*)&y1p;
  float4 o0, o1;
  o0.x = a0.x + bf2f(y0[0]) + bf2f(y1[0]);
  o0.y = a0.y + bf2f(y0[1]) + bf2f(y1[1]);
  o0.z = a0.z + bf2f(y0[2]) + bf2f(y1[2]);
  o0.w = a0.w + bf2f(y0[3]) + bf2f(y1[3]);
  o1.x = a1.x + bf2f(y0[4]) + bf2f(y1[4]);
  o1.y = a1.y + bf2f(y0[5]) + bf2f(y1[5]);
  o1.z = a1.z + bf2f(y0[6]) + bf2f(y1[6]);
  o1.w = a1.w + bf2f(y0[7]) + bf2f(y1[7]);
  ((float4*)out)[i * 2] = o0;
  ((float4*)out)[i * 2 + 1] = o1;
}

extern "C" void kernel_launch(void* const* d_in, const int* in_sizes, int n_in,
                              void* d_out, int out_size, void* d_ws, size_t ws_size,
                              hipStream_t stream) {
  const float* x     = (const float*)d_in[0];
  const float* ln1w  = (const float*)d_in[1];
  const float* attnw = (const float*)d_in[2];
  const float* projw = (const float*)d_in[3];
  const float* ln2w  = (const float*)d_in[4];
  const float* routw = (const float*)d_in[5];
  const float* w1    = (const float*)d_in[6];
  const float* w2    = (const float*)d_in[7];
  char* ws = (char*)d_ws;

  unsigned short* attn_wT = (unsigned short*)(ws + 0);          //  6,291,456
  unsigned short* proj_wT = (unsigned short*)(ws + 6291456);    //  2,097,152
  unsigned short* w1T     = (unsigned short*)(ws + 8388608);    // 33,554,432
  unsigned short* w2T     = (unsigned short*)(ws + 41943040);   // 33,554,432
  unsigned short* xn      = (unsigned short*)(ws + 75497472);   //  8,388,608
  unsigned short* qkv     = (unsigned short*)(ws + 83886080);   // 25,165,824
  unsigned short* yattn   = (unsigned short*)(ws + 109051904);  //  8,388,608
  unsigned short* hbuf    = (unsigned short*)(ws + 83886080);   // alias qkv+yattn (dead by then)
  float* x2 = (float*)(ws + 117440512);                         // 16,777,216
  float* Opart = x2;                     // split partials alias x2 (dead until proj)
  float* mlbuf = x2 + 4194304;
  unsigned short* ypb = (unsigned short*)(ws + 134217728);      // 16,777,216 bf16
  char* rbase = ws + 167772160;
  int* counts_pad  = (int*)(rbase);
  int* counts      = (int*)(rbase + 512);
  int* cursors_pad = (int*)(rbase + 1024);
  int* offs        = (int*)(rbase + 1536);
  int* tmap        = (int*)(rbase + 1600);
  int* tmap64      = (int*)(rbase + 1664);
  int* sel         = (int*)(rbase + 2048);
  float* selw      = (float*)(rbase + 2048 + 32768);
  int* tokarr      = (int*)(rbase + 2048 + 65536);
  int* slotarr     = (int*)(rbase + 2048 + 98304);
  float* wgtarr    = (float*)(rbase + 2048 + 131072);
  float* outp = (float*)d_out;

  hipMemsetAsync(counts_pad, 0, 512, stream);

  dim3 tb(32, 8);
  k_transpose<<<dim3(96, 32, 1), tb, 0, stream>>>(attnw, attn_wT, 1024, 3072);
  k_transpose<<<dim3(32, 32, 1), tb, 0, stream>>>(projw, proj_wT, 1024, 1024);
  k_transpose<<<dim3(512, 32, 1), tb, 0, stream>>>(w1, w1T, 1024, 16384);
  k_transpose<<<dim3(32, 64, 8), tb, 0, stream>>>(w2, w2T, 2048, 1024);

  k_ln<<<NTOK, 256, 0, stream>>>(x, ln1w, xn);
  k_gemm128<0><<<dim3(32, 24), 256, 0, stream>>>(xn, attn_wT, qkv, nullptr, nullptr,
      NTOK, 3 * CCH, CCH, nullptr, nullptr, nullptr, nullptr, nullptr, nullptr);
  k_attn_mfma<<<dim3(1536), 256, 0, stream>>>(qkv, yattn, Opart, mlbuf);
  k_attn_merge<<<dim3(512), 256, 0, stream>>>(Opart, mlbuf, yattn);
  // proj + residual: BM=64 -> 512 blocks (2/CU vs 1/CU at BM=128)
  k_gemm64<1><<<dim3(64, 8), 256, 0, stream>>>(yattn, proj_wT, nullptr, x2, x,
      NTOK, CCH, CCH, nullptr, nullptr, nullptr, nullptr, nullptr, nullptr);
  k_ln2_router<<<NTOK, 256, 0, stream>>>(x2, ln2w, routw, xn, sel, selw);
  k_count<<<32, 256, 0, stream>>>(sel, counts_pad);
  k_offsets<<<1, 64, 0, stream>>>(counts_pad, counts, offs, cursors_pad, tmap, tmap64);
  k_scatter<<<NTOK / 256, 256, 0, stream>>>(sel, selw, cursors_pad, tokarr, slotarr, wgtarr);
  k_gemm128<2><<<dim3(72, 16), 256, 0, stream>>>(xn, w1T, hbuf, nullptr, nullptr,
      NTOK, FF, CCH, tokarr, slotarr, wgtarr, offs, counts, tmap);
  // MoE down: BM=64 grouped -> ~1090 active blocks (4/CU vs 2/CU)
  k_gemm64<3><<<dim3(144, 8), 256, 0, stream>>>(hbuf, w2T, ypb, nullptr, nullptr,
      NTOK, CCH, FF, tokarr, slotarr, wgtarr, offs, counts, tmap64);
  k_combine<<<2048, 256, 0, stream>>>(x2, ypb, outp);
}

// Round 20
// 371.465 us; speedup vs baseline: 1.0112x; 1.0112x over previous
//
#include <hip/hip_runtime.h>
#include <hip/hip_bf16.h>

#define BB 2
#define TT 2048
#define CCH 1024
#define HH 16
#define HD 64
#define EE 8
#define FF 2048
#define NTOK (BB*TT)

typedef __bf16 bf16x8 __attribute__((ext_vector_type(8)));
typedef float f32x4 __attribute__((ext_vector_type(4)));
typedef unsigned int u32;
typedef const u32 __attribute__((address_space(1)))* gads;
typedef u32 __attribute__((address_space(3)))* lads;

static __device__ __forceinline__ unsigned short f2bf(float f) {
  union { float f; unsigned u; } v; v.f = f;
  unsigned u = v.u;
  u += 0x7fffu + ((u >> 16) & 1u);
  return (unsigned short)(u >> 16);
}
static __device__ __forceinline__ float bf2f(unsigned short h) {
  union { unsigned u; float f; } v; v.u = ((unsigned)h) << 16;
  return v.f;
}

// ---------------- transpose fp32 (R x C) -> bf16 (C x R), batched over z ----
__global__ __launch_bounds__(256) void k_transpose(const float* __restrict__ in,
    unsigned short* __restrict__ out, int R, int Cc) {
  __shared__ float tile[32][33];
  size_t zoff = (size_t)blockIdx.z * (size_t)R * (size_t)Cc;
  int r0 = blockIdx.y * 32, c0 = blockIdx.x * 32;
  int tx = threadIdx.x, ty = threadIdx.y;
#pragma unroll
  for (int ii = 0; ii < 4; ++ii) {
    int i = ty + ii * 8;
    tile[i][tx] = in[zoff + (size_t)(r0 + i) * Cc + c0 + tx];
  }
  __syncthreads();
#pragma unroll
  for (int ii = 0; ii < 4; ++ii) {
    int i = ty + ii * 8;
    out[zoff + (size_t)(c0 + i) * R + r0 + tx] = f2bf(tile[tx][i]);
  }
}

// ---------------- layernorm row kernel: fp32 in -> bf16 out ----------------
__global__ __launch_bounds__(256) void k_ln(const float* __restrict__ x,
    const float* __restrict__ w, unsigned short* __restrict__ out) {
  int row = blockIdx.x;
  const float* xr = x + (size_t)row * CCH;
  int tid = threadIdx.x;
  float4 v = *(const float4*)&xr[tid * 4];
  float s = v.x + v.y + v.z + v.w;
  float ss = v.x * v.x + v.y * v.y + v.z * v.z + v.w * v.w;
#pragma unroll
  for (int off = 32; off; off >>= 1) { s += __shfl_xor(s, off); ss += __shfl_xor(ss, off); }
  __shared__ float red[8];
  int wv = tid >> 6, l = tid & 63;
  if (l == 0) { red[wv] = s; red[4 + wv] = ss; }
  __syncthreads();
  s = red[0] + red[1] + red[2] + red[3];
  ss = red[4] + red[5] + red[6] + red[7];
  float mean = s * (1.f / CCH);
  float var = ss * (1.f / CCH) - mean * mean;
  float inv = rsqrtf(var + 1e-5f);
  float4 w4 = *(const float4*)&w[tid * 4];
  ushort4 o;
  o.x = f2bf((v.x - mean) * inv * w4.x);
  o.y = f2bf((v.y - mean) * inv * w4.y);
  o.z = f2bf((v.z - mean) * inv * w4.z);
  o.w = f2bf((v.w - mean) * inv * w4.w);
  *(ushort4*)&out[(size_t)row * CCH + tid * 4] = o;
}

// ---------------- fused LN2 + router: LN(bf16 out) + logits + top2 ---------
__global__ __launch_bounds__(256) void k_ln2_router(const float* __restrict__ x,
    const float* __restrict__ w, const float* __restrict__ rw,
    unsigned short* __restrict__ out, int* __restrict__ sel,
    float* __restrict__ selw) {
  int row = blockIdx.x;
  const float* xr = x + (size_t)row * CCH;
  int tid = threadIdx.x;
  float4 v = *(const float4*)&xr[tid * 4];
  float s = v.x + v.y + v.z + v.w;
  float ss = v.x * v.x + v.y * v.y + v.z * v.z + v.w * v.w;
#pragma unroll
  for (int off = 32; off; off >>= 1) { s += __shfl_xor(s, off); ss += __shfl_xor(ss, off); }
  __shared__ float red[8];
  __shared__ float red2[4][8];
  int wv = tid >> 6, l = tid & 63;
  if (l == 0) { red[wv] = s; red[4 + wv] = ss; }
  __syncthreads();
  s = red[0] + red[1] + red[2] + red[3];
  ss = red[4] + red[5] + red[6] + red[7];
  float mean = s * (1.f / CCH);
  float var = ss * (1.f / CCH) - mean * mean;
  float inv = rsqrtf(var + 1e-5f);
  float4 w4 = *(const float4*)&w[tid * 4];
  float nv0 = (v.x - mean) * inv * w4.x;
  float nv1 = (v.y - mean) * inv * w4.y;
  float nv2 = (v.z - mean) * inv * w4.z;
  float nv3 = (v.w - mean) * inv * w4.w;
  ushort4 o;
  o.x = f2bf(nv0); o.y = f2bf(nv1); o.z = f2bf(nv2); o.w = f2bf(nv3);
  *(ushort4*)&out[(size_t)row * CCH + tid * 4] = o;
  const float* rr = rw + (size_t)tid * 4 * EE;
  float lg[8];
#pragma unroll
  for (int e = 0; e < 8; ++e)
    lg[e] = nv0 * rr[e] + nv1 * rr[8 + e] + nv2 * rr[16 + e] + nv3 * rr[24 + e];
#pragma unroll
  for (int e = 0; e < 8; ++e) {
    float t = lg[e];
#pragma unroll
    for (int off = 32; off; off >>= 1) t += __shfl_xor(t, off);
    lg[e] = t;
  }
  if (l == 0) {
#pragma unroll
    for (int e = 0; e < 8; ++e) red2[wv][e] = lg[e];
  }
  __syncthreads();
  if (tid == 0) {
    float logit[8];
#pragma unroll
    for (int e = 0; e < 8; ++e)
      logit[e] = red2[0][e] + red2[1][e] + red2[2][e] + red2[3][e];
    float m1 = logit[0]; int i1 = 0;
#pragma unroll
    for (int e = 1; e < 8; ++e) if (logit[e] > m1) { m1 = logit[e]; i1 = e; }
    float m2 = -INFINITY; int i2 = 0;
#pragma unroll
    for (int e = 0; e < 8; ++e) if (e != i1 && logit[e] > m2) { m2 = logit[e]; i2 = e; }
    float w1v = 1.f / (1.f + __expf(m2 - m1));
    sel[row * 2] = i1; sel[row * 2 + 1] = i2;
    selw[row * 2] = w1v; selw[row * 2 + 1] = 1.f - w1v;
  }
}

// ---------------- 128x128 GEMM, single-buffer, TLP-first -------------------
#define CSP 140
#define CFP 70
template<int EPI>
__global__ __launch_bounds__(256, 4) void k_gemm128(
    const unsigned short* __restrict__ A, const unsigned short* __restrict__ BT,
    unsigned short* __restrict__ Cb, float* __restrict__ Cf,
    const float* __restrict__ resid, int M, int N, int K,
    const int* __restrict__ tokarr, const int* __restrict__ slotarr,
    const float* __restrict__ wgtarr, const int* __restrict__ offs,
    const int* __restrict__ counts, const int* __restrict__ tmap)
{
  __shared__ __align__(16) char pool[35840];
  unsigned short* As = (unsigned short*)pool;
  unsigned short* Bs = (unsigned short*)(pool + 16384);

  int mb, nb, e = 0, off = 0, cnt = M;
  if (EPI >= 2) {
    int tm = blockIdx.x;
    if (tm >= tmap[8]) return;
    e = 0;
    while (tm >= tmap[e + 1]) ++e;
    mb = tm - tmap[e];
    nb = blockIdx.y;
    cnt = counts[e]; off = offs[e];
  } else {
    int gx = gridDim.x, gy = gridDim.y;
    int nwg = gx * gy;
    int orig = blockIdx.y * gx + blockIdx.x;
    int q = nwg >> 3, r = nwg & 7;
    int xcd = orig & 7, idx = orig >> 3;
    int wk = (xcd < r ? xcd * (q + 1) : r * (q + 1) + (xcd - r) * q) + idx;
    nb = wk % gy; mb = wk / gy;
  }
  int m0 = mb * 128, n0 = nb * 128;

  int tid = threadIdx.x, l = tid & 63, w = tid >> 6;
  int scol = (((l & 7) ^ ((l >> 3) & 7)) * 8);
  const unsigned short* aptr[4];
  const unsigned short* bptr[4];
  const unsigned short* bbase = BT + (size_t)e * (size_t)N * K;
#pragma unroll
  for (int i = 0; i < 4; ++i) {
    int row = (w * 4 + i) * 8 + (l >> 3);
    int ra;
    if (EPI == 2)      ra = tokarr[off + min(m0 + row, cnt - 1)];
    else if (EPI == 3) ra = off + min(m0 + row, cnt - 1);
    else               ra = m0 + row;
    aptr[i] = A + (size_t)ra * K + scol;
    bptr[i] = bbase + (size_t)(n0 + row) * K + scol;
  }

  int wr = (w >> 1) * 64, wc = (w & 1) * 64;
  int frow = l & 15;
  int fkB = (l >> 4) * 16;
  int swz = (frow & 7) << 4;
  f32x4 acc[4][4] = {};

  for (int k0 = 0; k0 < K; k0 += 64) {
#pragma unroll
    for (int i = 0; i < 4; ++i) {
      int j = w * 4 + i;
      __builtin_amdgcn_global_load_lds((gads)(const void*)(aptr[i] + k0),
                                       (lads)(void*)(As + j * 512), 16, 0, 0);
      __builtin_amdgcn_global_load_lds((gads)(const void*)(bptr[i] + k0),
                                       (lads)(void*)(Bs + j * 512), 16, 0, 0);
    }
    __syncthreads();
    const char* ab = (const char*)As;
    const char* bb = (const char*)Bs;
#pragma unroll
    for (int kk = 0; kk < 2; ++kk) {
      int inr = (kk * 64 + fkB) ^ swz;
      bf16x8 af[4], bfr[4];
#pragma unroll
      for (int mi = 0; mi < 4; ++mi)
        af[mi] = *(const bf16x8*)(ab + (wr + mi * 16 + frow) * 128 + inr);
#pragma unroll
      for (int ni = 0; ni < 4; ++ni)
        bfr[ni] = *(const bf16x8*)(bb + (wc + ni * 16 + frow) * 128 + inr);
#pragma unroll
      for (int mi = 0; mi < 4; ++mi)
#pragma unroll
        for (int ni = 0; ni < 4; ++ni)
          acc[mi][ni] = __builtin_amdgcn_mfma_f32_16x16x32_bf16(af[mi], bfr[ni],
                                                                acc[mi][ni], 0, 0, 0);
    }
    __syncthreads();
  }

  int g4 = (l >> 4) * 4, cl = l & 15;

  if (EPI == 0 || EPI == 2 || EPI == 3) {
    unsigned short* Cs = (unsigned short*)pool;
#pragma unroll
    for (int mi = 0; mi < 4; ++mi)
#pragma unroll
      for (int ni = 0; ni < 4; ++ni)
#pragma unroll
        for (int r2 = 0; r2 < 4; ++r2) {
          float v = acc[mi][ni][r2];
          if (EPI == 2) {
            float u2 = 1.5957691216f * v * (1.f + 0.044715f * v * v);
            float ex = __expf(u2);
            v = v - v / (ex + 1.f);
          }
          Cs[(wr + mi * 16 + g4 + r2) * CSP + wc + ni * 16 + cl] = f2bf(v);
        }
    __syncthreads();
    int row = tid >> 1, c0 = (tid & 1) * 64;
    if (EPI == 0 || m0 + row < cnt) {
      if (EPI == 3) {
        int fl = off + m0 + row;
        int tok = tokarr[fl], slot = slotarr[fl];
        float wg = wgtarr[fl];
        unsigned short* dst = Cb + ((size_t)tok * 2 + slot) * N + n0 + c0;
#pragma unroll
        for (int j = 0; j < 8; ++j) {
          uint4 pk = *(const uint4*)&Cs[row * CSP + c0 + j * 8];
          unsigned short* sp = (unsigned short*)&pk;
          ushort4 o0, o1;
          o0.x = f2bf(bf2f(sp[0]) * wg); o0.y = f2bf(bf2f(sp[1]) * wg);
          o0.z = f2bf(bf2f(sp[2]) * wg); o0.w = f2bf(bf2f(sp[3]) * wg);
          o1.x = f2bf(bf2f(sp[4]) * wg); o1.y = f2bf(bf2f(sp[5]) * wg);
          o1.z = f2bf(bf2f(sp[6]) * wg); o1.w = f2bf(bf2f(sp[7]) * wg);
          *(ushort4*)&dst[j * 8] = o0;
          *(ushort4*)&dst[j * 8 + 4] = o1;
        }
      } else {
        size_t grow = (EPI == 2) ? (size_t)(off + m0 + row) : (size_t)(m0 + row);
        unsigned short* dst = Cb + grow * N + n0 + c0;
#pragma unroll
        for (int j = 0; j < 8; ++j)
          ((uint4*)dst)[j] = *(const uint4*)&Cs[row * CSP + c0 + j * 8];
      }
    }
  } else {
    float* Csf = (float*)pool;
#pragma unroll
    for (int p = 0; p < 2; ++p) {
      __syncthreads();
      if ((w & 1) == p) {
#pragma unroll
        for (int mi = 0; mi < 4; ++mi)
#pragma unroll
          for (int ni = 0; ni < 4; ++ni)
#pragma unroll
            for (int r2 = 0; r2 < 4; ++r2)
              Csf[(wr + mi * 16 + g4 + r2) * CFP + ni * 16 + cl] = acc[mi][ni][r2];
      }
      __syncthreads();
      int row = tid >> 1, c0 = (tid & 1) * 32;
      int gcol = n0 + p * 64 + c0;
      float* dst = Cf + (size_t)(m0 + row) * N + gcol;
      const float* rsd = resid + (size_t)(m0 + row) * N + gcol;
#pragma unroll
      for (int j = 0; j < 8; ++j) {
        float4 v = *(const float4*)&Csf[row * CFP + c0 + j * 4];
        float4 rr = ((const float4*)rsd)[j];
        v.x += rr.x; v.y += rr.y; v.z += rr.z; v.w += rr.w;
        ((float4*)dst)[j] = v;
      }
    }
  }
}

// ---------------- MFMA flash attention, KV-split (r18 proven) --------------
__device__ const unsigned char g_witab[48] = {
  124,125,120, 62, 121,116,117,112, 58, 113,108,109,104, 54,
  105,100,101, 96, 50,  97, 92, 93, 88, 46,  89, 84, 85, 80, 42,
   81, 76, 77, 72, 38,  73, 68, 69, 64, 34,  65, 30, 26, 22, 18, 14, 10, 6, 2
};

__global__ __launch_bounds__(256) void k_attn_mfma(const unsigned short* __restrict__ qkv,
    unsigned short* __restrict__ yout, float* __restrict__ Opart, float* __restrict__ ml)
{
  int fblk = blockIdx.x;
  int xcd = fblk & 7, s = fblk >> 3;
  int hbl = s & 3;
  int h = xcd + 8 * (hbl & 1);
  int b = hbl >> 1;
  int item = s >> 2;
  int v = g_witab[item];
  int qt = v >> 2, code = v & 3;
  bool split = (code != 2);
  int h1 = (qt + 2) >> 1;
  int kb0 = (code == 1) ? h1 : 0;
  int kb1 = (code == 0) ? h1 : (qt + 1);
  int q0 = qt * 64;

  int tid = threadIdx.x, l = tid & 63, w = tid >> 6;
  const size_t rs = 3 * CCH;

  __shared__ __align__(16) unsigned short Ks[64][72];
  __shared__ __align__(16) unsigned short VtL[64 * 72];
  __shared__ __align__(16) unsigned short Ps[4][16][72];

  int frow = l & 15, fk = (l >> 4) * 8;
  int g4 = l >> 4;
  int kr = tid >> 2, kc0 = (tid & 3) * 8;
  int vr = tid >> 2, vc0 = (tid & 3) * 16;
  int vphys = (((vr >> 3) + 2 * (tid & 3)) & 7) * 8 + (vr & 7);

  const unsigned short* qp = qkv + (size_t)((size_t)b * TT + q0 + w * 16 + frow) * rs + h * HD;
  bf16x8 qf0 = *(const bf16x8*)&qp[fk];
  bf16x8 qf1 = *(const bf16x8*)&qp[32 + fk];
  {
    unsigned short* q0s = (unsigned short*)&qf0;
    unsigned short* q1s = (unsigned short*)&qf1;
#pragma unroll
    for (int j = 0; j < 8; ++j) {
      q0s[j] = f2bf(bf2f(q0s[j]) * 0.125f);
      q1s[j] = f2bf(bf2f(q1s[j]) * 0.125f);
    }
  }

  f32x4 oacc[4] = {};
  float mrow[4] = {-INFINITY, -INFINITY, -INFINITY, -INFINITY};
  float lrow[4] = {};

  uint4 rk0, rk1, rv0, rv1;
  {
    int k0 = kb0 * 64;
    const unsigned short* kp = qkv + (size_t)((size_t)b * TT + k0 + kr) * rs + CCH + h * HD;
    rk0 = *(const uint4*)&kp[kc0];
    rk1 = *(const uint4*)&kp[kc0 + 32];
    const unsigned short* vp = qkv + (size_t)((size_t)b * TT + k0 + vr) * rs + 2 * CCH + h * HD + vc0;
    rv0 = *(const uint4*)&vp[0];
    rv1 = *(const uint4*)&vp[8];
  }

  for (int kb = kb0; kb < kb1; ++kb) {
    __syncthreads();
    *(uint4*)&Ks[kr][kc0]      = rk0;
    *(uint4*)&Ks[kr][kc0 + 32] = rk1;
    {
      unsigned short tmp[16];
      *(uint4*)&tmp[0] = rv0; *(uint4*)&tmp[8] = rv1;
#pragma unroll
      for (int j = 0; j < 16; ++j) VtL[(vc0 + j) * 72 + vphys] = tmp[j];
    }
    __syncthreads();
    if (kb + 1 < kb1) {
      int k0n = (kb + 1) * 64;
      const unsigned short* kp = qkv + (size_t)((size_t)b * TT + k0n + kr) * rs + CCH + h * HD;
      rk0 = *(const uint4*)&kp[kc0];
      rk1 = *(const uint4*)&kp[kc0 + 32];
      const unsigned short* vp = qkv + (size_t)((size_t)b * TT + k0n + vr) * rs + 2 * CCH + h * HD + vc0;
      rv0 = *(const uint4*)&vp[0];
      rv1 = *(const uint4*)&vp[8];
    }

    f32x4 sacc[4] = {};
    __builtin_amdgcn_s_setprio(1);
#pragma unroll
    for (int nb = 0; nb < 4; ++nb) {
      bf16x8 kf0 = *(const bf16x8*)&Ks[nb * 16 + frow][fk];
      bf16x8 kf1 = *(const bf16x8*)&Ks[nb * 16 + frow][32 + fk];
      sacc[nb] = __builtin_amdgcn_mfma_f32_16x16x32_bf16(qf0, kf0, sacc[nb], 0, 0, 0);
      sacc[nb] = __builtin_amdgcn_mfma_f32_16x16x32_bf16(qf1, kf1, sacc[nb], 0, 0, 0);
    }
    __builtin_amdgcn_s_setprio(0);

    bool diag = (kb == qt);
    float sv[4][4];
#pragma unroll
    for (int nb = 0; nb < 4; ++nb)
#pragma unroll
      for (int r = 0; r < 4; ++r) {
        float vv = sacc[nb][r];
        if (diag) {
          int ckv = nb * 16 + frow;
          int rq = w * 16 + 4 * g4 + r;
          if (ckv > rq) vv = -INFINITY;
        }
        sv[nb][r] = vv;
      }
    float fscale[4];
#pragma unroll
    for (int r = 0; r < 4; ++r) {
      float vm = fmaxf(fmaxf(sv[0][r], sv[1][r]), fmaxf(sv[2][r], sv[3][r]));
      vm = fmaxf(vm, __shfl_xor(vm, 1));
      vm = fmaxf(vm, __shfl_xor(vm, 2));
      vm = fmaxf(vm, __shfl_xor(vm, 4));
      vm = fmaxf(vm, __shfl_xor(vm, 8));
      float mnew = fmaxf(mrow[r], vm);
      float f = __expf(mrow[r] - mnew);
      mrow[r] = mnew;
      fscale[r] = f;
      float psum = 0.f;
#pragma unroll
      for (int nb = 0; nb < 4; ++nb) {
        float p = __expf(sv[nb][r] - mnew);
        sv[nb][r] = p;
        psum += p;
      }
      psum += __shfl_xor(psum, 1);
      psum += __shfl_xor(psum, 2);
      psum += __shfl_xor(psum, 4);
      psum += __shfl_xor(psum, 8);
      lrow[r] = lrow[r] * f + psum;
    }
#pragma unroll
    for (int nb = 0; nb < 4; ++nb)
#pragma unroll
      for (int r = 0; r < 4; ++r) {
        oacc[nb][r] *= fscale[r];
        Ps[w][4 * g4 + r][nb * 16 + frow] = f2bf(sv[nb][r]);
      }
    __builtin_amdgcn_s_setprio(1);
#pragma unroll
    for (int ks = 0; ks < 2; ++ks) {
      bf16x8 pa = *(const bf16x8*)&Ps[w][frow][ks * 32 + fk];
#pragma unroll
      for (int nb = 0; nb < 4; ++nb) {
        int vchunk = ((ks * 4 + (l >> 4) + 2 * nb) & 7) * 8;
        bf16x8 vb = *(const bf16x8*)&VtL[(nb * 16 + frow) * 72 + vchunk];
        oacc[nb] = __builtin_amdgcn_mfma_f32_16x16x32_bf16(pa, vb, oacc[nb], 0, 0, 0);
      }
    }
    __builtin_amdgcn_s_setprio(0);
  }

  if (!split) {
    unsigned short* yo = yout + (size_t)((size_t)b * TT + q0 + w * 16) * CCH + h * HD;
#pragma unroll
    for (int r = 0; r < 4; ++r) {
      float inv = 1.f / lrow[r];
      int row = 4 * g4 + r;
#pragma unroll
      for (int nb = 0; nb < 4; ++nb)
        yo[(size_t)row * CCH + nb * 16 + frow] = f2bf(oacc[nb][r] * inv);
    }
  } else {
    int hbg = b * HH + h;
    int pid = hbg * 16 + (qt - 16);
    int part = pid * 2 + code;
    float* Op = Opart + (size_t)part * 4096;
#pragma unroll
    for (int r = 0; r < 4; ++r) {
      int row = w * 16 + 4 * g4 + r;
#pragma unroll
      for (int nb = 0; nb < 4; ++nb)
        Op[row * 64 + nb * 16 + frow] = oacc[nb][r];
    }
    if (frow == 0) {
      float* mlp = ml + (size_t)part * 128;
#pragma unroll
      for (int r = 0; r < 4; ++r) {
        int row = w * 16 + 4 * g4 + r;
        mlp[row] = mrow[r];
        mlp[64 + row] = lrow[r];
      }
    }
  }
}

// ---------------- attention split-merge: combine two KV halves -------------
__global__ __launch_bounds__(256) void k_attn_merge(const float* __restrict__ Opart,
    const float* __restrict__ ml, unsigned short* __restrict__ yout)
{
  int pid = blockIdx.x;
  int hbg = pid >> 4;
  int qt = 16 + (pid & 15);
  int b = hbg >> 4, h = hbg & 15;
  int tid = threadIdx.x;
  int row = tid >> 2, c0 = (tid & 3) * 16;
  const float* mlA = ml + (size_t)(pid * 2) * 128;
  const float* mlB = mlA + 128;
  float mA = mlA[row], lA = mlA[64 + row];
  float mB = mlB[row], lB = mlB[64 + row];
  float m = fmaxf(mA, mB);
  float fA = __expf(mA - m), fB = __expf(mB - m);
  float inv = 1.f / (lA * fA + lB * fB);
  const float* OA = Opart + (size_t)(pid * 2) * 4096 + row * 64 + c0;
  const float* OB = OA + 4096;
  unsigned short* yo = yout + ((size_t)b * TT + qt * 64 + row) * CCH + h * HD + c0;
#pragma unroll
  for (int j4 = 0; j4 < 4; ++j4) {
    float4 a = *(const float4*)&OA[j4 * 4];
    float4 bb = *(const float4*)&OB[j4 * 4];
    ushort4 o;
    o.x = f2bf((a.x * fA + bb.x * fB) * inv);
    o.y = f2bf((a.y * fA + bb.y * fB) * inv);
    o.z = f2bf((a.z * fA + bb.z * fB) * inv);
    o.w = f2bf((a.w * fA + bb.w * fB) * inv);
    *(ushort4*)&yo[j4 * 4] = o;
  }
}

// ---------------- count: LDS histogram -> 1 atomic/expert/block ------------
__global__ __launch_bounds__(256) void k_count(const int* __restrict__ sel,
    int* __restrict__ counts_pad)
{
  __shared__ int hist[8];
  int tid = threadIdx.x;
  if (tid < 8) hist[tid] = 0;
  __syncthreads();
  int i = blockIdx.x * 256 + tid;
  atomicAdd(&hist[sel[i]], 1);
  __syncthreads();
  if (tid < 8) atomicAdd(&counts_pad[tid * 16], hist[tid]);
}

__global__ void k_offsets(const int* __restrict__ counts_pad, int* __restrict__ counts,
                          int* __restrict__ offs, int* __restrict__ cursors_pad,
                          int* __restrict__ tmap) {
  if (threadIdx.x == 0 && blockIdx.x == 0) {
    int acc = 0, t = 0;
    tmap[0] = 0;
    for (int e = 0; e < 8; ++e) {
      int c = counts_pad[e * 16];
      counts[e] = c; offs[e] = acc; cursors_pad[e * 16] = acc; acc += c;
      t += (c + 127) >> 7;
      tmap[e + 1] = t;
    }
  }
}

// ---------------- scatter: wave-aggregated ballot atomics ------------------
__global__ __launch_bounds__(256) void k_scatter(const int* __restrict__ sel,
    const float* __restrict__ selw, int* __restrict__ cursors_pad,
    int* __restrict__ tokarr, int* __restrict__ slotarr, float* __restrict__ wgtarr)
{
  int t = blockIdx.x * 256 + threadIdx.x;
  int l = threadIdx.x & 63;
#pragma unroll
  for (int s2 = 0; s2 < 2; ++s2) {
    int e = sel[t * 2 + s2];
    int pos = 0;
#pragma unroll
    for (int ex = 0; ex < 8; ++ex) {
      unsigned long long mask = __ballot(e == ex);
      if (e == ex) {
        int leader = __ffsll((long long)mask) - 1;
        int cntw = __popcll(mask);
        int base = 0;
        if (l == leader) base = atomicAdd(&cursors_pad[ex * 16], cntw);
        base = __shfl(base, leader);
        unsigned long long below = (l == 0) ? 0ull : (mask << (64 - l));
        pos = base + __popcll(below);
      }
    }
    tokarr[pos] = t; slotarr[pos] = s2; wgtarr[pos] = selw[t * 2 + s2];
  }
}

// ---------------- final combine: out = x2 + yp[:,0,:] + yp[:,1,:] (yp bf16)-
__global__ __launch_bounds__(256) void k_combine(const float* __restrict__ x2,
    const unsigned short* __restrict__ ypb, float* __restrict__ out)
{
  int i = blockIdx.x * 256 + threadIdx.x;
  int n = i >> 7, cw = i & 127;
  float4 a0 = ((const float4*)x2)[i * 2];
  float4 a1 = ((const float4*)x2)[i * 2 + 1];
  uint4 y0p = *(const uint4*)&ypb[((size_t)n * 2) * CCH + cw * 8];
  uint4 y1p = *(const uint4*)&ypb[((size_t)n * 2 + 1) * CCH + cw * 8];
  const unsigned short* y0 = (const unsigned short*)&y0p;
  const unsigned short* y1 = (const unsigned short*)&y1p;
  float4 o0, o1;
  o0.x = a0.x + bf2f(y0[0]) + bf2f(y1[0]);
  o0.y = a0.y + bf2f(y0[1]) + bf2f(y1[1]);
  o0.z = a0.z + bf2f(y0[2]) + bf2f(y1[2]);
  o0.w = a0.w + bf2f(y0[3]) + bf2f(y1[3]);
  o1.x = a1.x + bf2f(y0[4]) + bf2f(y1[4]);
  o1.y = a1.y + bf2f(y0[5]) + bf2f(y1[5]);
  o1.z = a1.z + bf2f(y0[6]) + bf2f(y1[6]);
  o1.w = a1.w + bf2f(y0[7]) + bf2f(y1[7]);
  ((float4*)out)[i * 2] = o0;
  ((float4*)out)[i * 2 + 1] = o1;
}

extern "C" void kernel_launch(void* const* d_in, const int* in_sizes, int n_in,
                              void* d_out, int out_size, void* d_ws, size_t ws_size,
                              hipStream_t stream) {
  const float* x     = (const float*)d_in[0];
  const float* ln1w  = (const float*)d_in[1];
  const float* attnw = (const float*)d_in[2];
  const float* projw = (const float*)d_in[3];
  const float* ln2w  = (const float*)d_in[4];
  const float* routw = (const float*)d_in[5];
  const float* w1    = (const float*)d_in[6];
  const float* w2    = (const float*)d_in[7];
  char* ws = (char*)d_ws;

  unsigned short* attn_wT = (unsigned short*)(ws + 0);
  unsigned short* proj_wT = (unsigned short*)(ws + 6291456);
  unsigned short* w1T     = (unsigned short*)(ws + 8388608);
  unsigned short* w2T     = (unsigned short*)(ws + 41943040);
  unsigned short* xn      = (unsigned short*)(ws + 75497472);
  unsigned short* qkv     = (unsigned short*)(ws + 83886080);
  unsigned short* yattn   = (unsigned short*)(ws + 109051904);
  unsigned short* hbuf    = (unsigned short*)(ws + 83886080);  // alias qkv+yattn
  float* x2 = (float*)(ws + 117440512);
  float* Opart = x2;                     // split partials alias x2 (dead until proj)
  float* mlbuf = x2 + 4194304;
  unsigned short* ypb = (unsigned short*)(ws + 134217728);
  char* rbase = ws + 167772160;
  int* counts_pad  = (int*)(rbase);
  int* counts      = (int*)(rbase + 512);
  int* cursors_pad = (int*)(rbase + 1024);
  int* offs        = (int*)(rbase + 1536);
  int* tmap        = (int*)(rbase + 1600);
  int* sel         = (int*)(rbase + 2048);
  float* selw      = (float*)(rbase + 2048 + 32768);
  int* tokarr      = (int*)(rbase + 2048 + 65536);
  int* slotarr     = (int*)(rbase + 2048 + 98304);
  float* wgtarr    = (float*)(rbase + 2048 + 131072);
  float* outp = (float*)d_out;

  hipMemsetAsync(counts_pad, 0, 512, stream);

  dim3 tb(32, 8);
  k_transpose<<<dim3(96, 32, 1), tb, 0, stream>>>(attnw, attn_wT, 1024, 3072);
  k_transpose<<<dim3(32, 32, 1), tb, 0, stream>>>(projw, proj_wT, 1024, 1024);
  k_transpose<<<dim3(512, 32, 1), tb, 0, stream>>>(w1, w1T, 1024, 16384);
  k_transpose<<<dim3(32, 64, 8), tb, 0, stream>>>(w2, w2T, 2048, 1024);

  k_ln<<<NTOK, 256, 0, stream>>>(x, ln1w, xn);
  k_gemm128<0><<<dim3(32, 24), 256, 0, stream>>>(xn, attn_wT, qkv, nullptr, nullptr,
      NTOK, 3 * CCH, CCH, nullptr, nullptr, nullptr, nullptr, nullptr, nullptr);
  k_attn_mfma<<<dim3(1536), 256, 0, stream>>>(qkv, yattn, Opart, mlbuf);
  k_attn_merge<<<dim3(512), 256, 0, stream>>>(Opart, mlbuf, yattn);
  k_gemm128<1><<<dim3(32, 8), 256, 0, stream>>>(yattn, proj_wT, nullptr, x2, x,
      NTOK, CCH, CCH, nullptr, nullptr, nullptr, nullptr, nullptr, nullptr);
  k_ln2_router<<<NTOK, 256, 0, stream>>>(x2, ln2w, routw, xn, sel, selw);
  k_count<<<32, 256, 0, stream>>>(sel, counts_pad);
  k_offsets<<<1, 64, 0, stream>>>(counts_pad, counts, offs, cursors_pad, tmap);
  k_scatter<<<NTOK / 256, 256, 0, stream>>>(sel, selw, cursors_pad, tokarr, slotarr, wgtarr);
  k_gemm128<2><<<dim3(72, 16), 256, 0, stream>>>(xn, w1T, hbuf, nullptr, nullptr,
      NTOK, FF, CCH, tokarr, slotarr, wgtarr, offs, counts, tmap);
  k_gemm128<3><<<dim3(72, 8), 256, 0, stream>>>(hbuf, w2T, ypb, nullptr, nullptr,
      NTOK, CCH, FF, tokarr, slotarr, wgtarr, offs, counts, tmap);
  k_combine<<<2048, 256, 0, stream>>>(x2, ypb, outp);
}